// Round 3
// baseline (118.073 us; speedup 1.0000x reference)
//
#include <hip/hip_runtime.h>
#include <hip/hip_bf16.h>

// SeqOuterProductMean on MI355X.
// T[j,p,d] = sum_f s2[j,f]*w3[p,d*32+f]          (GEMM2: M=384, N=4096,  K=32)
// pair[i, j*128+p] = sum_d s1[i,d]*T[j*128+p,d]  (GEMM3: M=384, N=49152, K=32)
// w3 flat [p][d*32+f] == [(p*32+d)][f] row-major -> GEMM2 B with no permute.
// GEMM2 out [384,4096] row-major == GEMM3 B [49152,32] row-major.
//
// R3: same as R2, with bf16x4 rename (short4 collides with HIP vector types).

typedef __attribute__((ext_vector_type(8))) short short8;   // 8 x bf16
typedef __attribute__((ext_vector_type(4))) short bf16x4;   // 4 x bf16
typedef __attribute__((ext_vector_type(4))) float f32x4;

static __device__ __forceinline__ short f2bf(float f) {
    unsigned u = __float_as_uint(f);
    unsigned r = u + 0x7fffu + ((u >> 16) & 1u);   // round-to-nearest-even
    return (short)(r >> 16);
}

// ---------------------------------------------------------------------------
// K1: (blocks 0..L-1) LayerNorm + both H=32 projections, one block per row.
//     (blocks L..L+511) cast w3 (131072 floats) to bf16, 256 elems/block.
// ---------------------------------------------------------------------------
__global__ __launch_bounds__(256) void ln_proj_cast_kernel(
    const float* __restrict__ seq, const float* __restrict__ gamma,
    const float* __restrict__ beta, const float* __restrict__ w1,
    const float* __restrict__ b1, const float* __restrict__ w2,
    const float* __restrict__ b2, const float* __restrict__ w3,
    short* __restrict__ s1, short* __restrict__ s2, short* __restrict__ w3c,
    int L) {
    const int t = threadIdx.x;

    if (blockIdx.x >= L) {                 // ---- cast branch ----
        int i = (blockIdx.x - L) * 256 + t;
        w3c[i] = f2bf(w3[i]);
        return;
    }

    const int row = blockIdx.x;
    const int wv = t >> 6;      // wave 0..3
    const int ln = t & 63;      // lane 0..63

    __shared__ float wsum[4];
    __shared__ float xln[256];
    __shared__ float part[4][64];

    float v = seq[row * 256 + t];

    // mean
    float s = v;
    #pragma unroll
    for (int off = 32; off > 0; off >>= 1) s += __shfl_down(s, off);
    if (ln == 0) wsum[wv] = s;
    __syncthreads();
    float mean = (wsum[0] + wsum[1] + wsum[2] + wsum[3]) * (1.0f / 256.0f);

    // variance
    float c = v - mean;
    float cs = c * c;
    #pragma unroll
    for (int off = 32; off > 0; off >>= 1) cs += __shfl_down(cs, off);
    __syncthreads();
    if (ln == 0) wsum[wv] = cs;
    __syncthreads();
    float var = (wsum[0] + wsum[1] + wsum[2] + wsum[3]) * (1.0f / 256.0f);

    float xn = c * rsqrtf(var + 1e-5f) * gamma[t] + beta[t];
    xln[t] = xn;
    __syncthreads();

    // 64 outputs (s1: 0..31, s2: 32..63); wave wv covers dims [wv*64, wv*64+64).
    const float* w = (ln < 32) ? (w1 + ln * 256) : (w2 + (ln - 32) * 256);
    const f32x4* wp = (const f32x4*)(w + wv * 64);
    const float* xs = &xln[wv * 64];
    float p = 0.0f;
    #pragma unroll
    for (int i = 0; i < 16; ++i) {
        f32x4 w4 = wp[i];
        p += xs[4*i + 0] * w4.x + xs[4*i + 1] * w4.y +
             xs[4*i + 2] * w4.z + xs[4*i + 3] * w4.w;
    }
    part[wv][ln] = p;
    __syncthreads();

    if (t < 64) {
        float r = part[0][t] + part[1][t] + part[2][t] + part[3][t];
        if (t < 32) { r += b1[t];      s1[row * 32 + t]        = f2bf(r); }
        else        { r += b2[t - 32]; s2[row * 32 + (t - 32)] = f2bf(r); }
    }
}

// ---------------------------------------------------------------------------
// K=32 skinny GEMM: D[M,N] = A[M,32] * B[N,32]^T (+ bias[n&127] if BIAS).
// Operand-swapped MFMA: acc = mfma(bfrag, afrag) so C/D rows = n -> each lane
// holds 4 consecutive n for fixed m=l15 -> one dwordx4 store per 16x16 tile.
// Block = 4 waves, each owning a 16-wide n column; MITERS m-tiles per wave.
// ---------------------------------------------------------------------------
template <typename OutT, bool BIAS, int MITERS>
__global__ __launch_bounds__(256, 4) void gemm_k32_kernel(
    const short* __restrict__ A, const short* __restrict__ B,
    OutT* __restrict__ D, const float* __restrict__ bias, int N) {
    const int lane = threadIdx.x & 63;
    const int wave = threadIdx.x >> 6;
    const int l15  = lane & 15;
    const int quad = lane >> 4;
    const int k0   = quad * 8;
    const int n0   = blockIdx.x * 64 + wave * 16;   // this wave's n tile
    const int mbeg = blockIdx.y * (MITERS * 16);

    // B fragment: rows n0+l15 (lane&15 = n), k = quad*8..quad*8+7
    short8 bfrag = *reinterpret_cast<const short8*>(B + (size_t)(n0 + l15) * 32 + k0);

    f32x4 bv = {0.0f, 0.0f, 0.0f, 0.0f};
    if (BIAS) bv = *reinterpret_cast<const f32x4*>(bias + ((n0 + quad * 4) & 127));

    const short* aptr = A + (size_t)(mbeg + l15) * 32 + k0;
    // store base: row m = mbeg + l15, col n = n0 + quad*4 (+r via float4 lanes)
    OutT* dptr = D + (size_t)(mbeg + l15) * N + n0 + quad * 4;
    const size_t dstep = (size_t)16 * N;

    short8 a_cur = *reinterpret_cast<const short8*>(aptr);
    #pragma unroll
    for (int it = 0; it < MITERS; ++it) {
        aptr += 16 * 32;
        short8 a_nxt;
        if (it + 1 < MITERS) a_nxt = *reinterpret_cast<const short8*>(aptr);

        f32x4 acc = {0.0f, 0.0f, 0.0f, 0.0f};
        acc = __builtin_amdgcn_mfma_f32_16x16x32_bf16(bfrag, a_cur, acc, 0, 0, 0);

        if constexpr (BIAS) acc += bv;   // fp32 path
        if constexpr (sizeof(OutT) == 4) {
            __builtin_nontemporal_store(acc, (f32x4*)dptr);   // write-once output
        } else {
            bf16x4 pv = { f2bf(acc.x), f2bf(acc.y), f2bf(acc.z), f2bf(acc.w) };
            *reinterpret_cast<bf16x4*>(dptr) = pv;            // T: keep in L2
        }
        dptr += dstep;
        a_cur = a_nxt;
    }
}

// ---------------------------------------------------------------------------
extern "C" void kernel_launch(void* const* d_in, const int* in_sizes, int n_in,
                              void* d_out, int out_size, void* d_ws, size_t ws_size,
                              hipStream_t stream) {
    const float* seq   = (const float*)d_in[0];
    const float* gamma = (const float*)d_in[1];
    const float* beta  = (const float*)d_in[2];
    const float* w1    = (const float*)d_in[3];
    const float* b1    = (const float*)d_in[4];
    const float* w2    = (const float*)d_in[5];
    const float* b2    = (const float*)d_in[6];
    const float* w3    = (const float*)d_in[7];
    const float* b3    = (const float*)d_in[8];
    float* out = (float*)d_out;

    const int L = 384, H = 32, P = 128;
    const int N2 = P * H;        // 4096
    const int N3 = L * P;        // 49152

    char* ws = (char*)d_ws;
    short* s1  = (short*)(ws);                        // 384*32*2   = 24576
    short* s2  = (short*)(ws + 24576);                // 24576
    short* w3c = (short*)(ws + 49152);                // 131072*2   = 262144
    short* T   = (short*)(ws + 311296);               // 384*4096*2 = 3145728

    // K1: LN + projections (blocks 0..383) + w3 cast (blocks 384..895)
    ln_proj_cast_kernel<<<L + (P * H * H) / 256, 256, 0, stream>>>(
        seq, gamma, beta, w1, b1, w2, b2, w3, s1, s2, w3c, L);

    // K2: T[j, p*32+d] = sum_f s2[j,f] * w3c[(p*32+d), f]   (bf16 out)
    // grid: 4096/64 n-blocks x 8 m-chunks (48 rows -> 3 m-tiles each)
    gemm_k32_kernel<short, false, 3><<<dim3(N2 / 64, 8), 256, 0, stream>>>(
        s2, w3c, T, nullptr, N2);

    // K3: pair[i, j*128+p] = sum_d s1[i,d] * T[(j*128+p), d] + b3[p]  (fp32 out)
    // grid: 49152/64 n-blocks x 2 m-chunks (192 rows -> 12 m-tiles each)
    gemm_k32_kernel<float, true, 12><<<dim3(N3 / 64, 2), 256, 0, stream>>>(
        s1, T, out, b3, N3);
}

// Round 4
// 113.088 us; speedup vs baseline: 1.0441x; 1.0441x over previous
//
#include <hip/hip_runtime.h>
#include <hip/hip_bf16.h>

// SeqOuterProductMean on MI355X.
// T[j,p,d] = sum_f s2[j,f]*w3[p,d*32+f]          (GEMM2: M=384, N=4096,  K=32)
// pair[i, j*128+p] = sum_d s1[i,d]*T[j*128+p,d]  (GEMM3: M=384, N=49152, K=32)
// w3 flat [p][d*32+f] == [(p*32+d)][f] row-major -> GEMM2 B with no permute.
// GEMM2 out [384,4096] row-major == GEMM3 B [49152,32] row-major.
//
// R4: K3 drops nontemporal stores (let L2/MALL write-back merge; 75.5 MB out
// fits in the 256 MiB L3) and widens waves to 16 rows x 32 cols (2 MFMAs per
// A-frag) so each wave-iter writes full 128 B lines per row. K1/K2 unchanged.

typedef __attribute__((ext_vector_type(8))) short short8;   // 8 x bf16
typedef __attribute__((ext_vector_type(4))) short bf16x4;   // 4 x bf16
typedef __attribute__((ext_vector_type(4))) float f32x4;

static __device__ __forceinline__ short f2bf(float f) {
    unsigned u = __float_as_uint(f);
    unsigned r = u + 0x7fffu + ((u >> 16) & 1u);   // round-to-nearest-even
    return (short)(r >> 16);
}

// ---------------------------------------------------------------------------
// K1: (blocks 0..L-1) LayerNorm + both H=32 projections, one block per row.
//     (blocks L..L+511) cast w3 (131072 floats) to bf16, 256 elems/block.
// ---------------------------------------------------------------------------
__global__ __launch_bounds__(256) void ln_proj_cast_kernel(
    const float* __restrict__ seq, const float* __restrict__ gamma,
    const float* __restrict__ beta, const float* __restrict__ w1,
    const float* __restrict__ b1, const float* __restrict__ w2,
    const float* __restrict__ b2, const float* __restrict__ w3,
    short* __restrict__ s1, short* __restrict__ s2, short* __restrict__ w3c,
    int L) {
    const int t = threadIdx.x;

    if (blockIdx.x >= L) {                 // ---- cast branch ----
        int i = (blockIdx.x - L) * 256 + t;
        w3c[i] = f2bf(w3[i]);
        return;
    }

    const int row = blockIdx.x;
    const int wv = t >> 6;      // wave 0..3
    const int ln = t & 63;      // lane 0..63

    __shared__ float wsum[4];
    __shared__ float xln[256];
    __shared__ float part[4][64];

    float v = seq[row * 256 + t];

    // mean
    float s = v;
    #pragma unroll
    for (int off = 32; off > 0; off >>= 1) s += __shfl_down(s, off);
    if (ln == 0) wsum[wv] = s;
    __syncthreads();
    float mean = (wsum[0] + wsum[1] + wsum[2] + wsum[3]) * (1.0f / 256.0f);

    // variance
    float c = v - mean;
    float cs = c * c;
    #pragma unroll
    for (int off = 32; off > 0; off >>= 1) cs += __shfl_down(cs, off);
    __syncthreads();
    if (ln == 0) wsum[wv] = cs;
    __syncthreads();
    float var = (wsum[0] + wsum[1] + wsum[2] + wsum[3]) * (1.0f / 256.0f);

    float xn = c * rsqrtf(var + 1e-5f) * gamma[t] + beta[t];
    xln[t] = xn;
    __syncthreads();

    // 64 outputs (s1: 0..31, s2: 32..63); wave wv covers dims [wv*64, wv*64+64).
    const float* w = (ln < 32) ? (w1 + ln * 256) : (w2 + (ln - 32) * 256);
    const f32x4* wp = (const f32x4*)(w + wv * 64);
    const float* xs = &xln[wv * 64];
    float p = 0.0f;
    #pragma unroll
    for (int i = 0; i < 16; ++i) {
        f32x4 w4 = wp[i];
        p += xs[4*i + 0] * w4.x + xs[4*i + 1] * w4.y +
             xs[4*i + 2] * w4.z + xs[4*i + 3] * w4.w;
    }
    part[wv][ln] = p;
    __syncthreads();

    if (t < 64) {
        float r = part[0][t] + part[1][t] + part[2][t] + part[3][t];
        if (t < 32) { r += b1[t];      s1[row * 32 + t]        = f2bf(r); }
        else        { r += b2[t - 32]; s2[row * 32 + (t - 32)] = f2bf(r); }
    }
}

// ---------------------------------------------------------------------------
// K2: K=32 skinny GEMM, bf16 out: T[M2=384 rows i.e. j, N=4096] (unchanged).
// Operand-swapped MFMA (C rows = n); each wave owns one 16-wide n column.
// ---------------------------------------------------------------------------
template <int MITERS>
__global__ __launch_bounds__(256, 4) void gemm_k32_bf16_kernel(
    const short* __restrict__ A, const short* __restrict__ B,
    short* __restrict__ D, int N) {
    const int lane = threadIdx.x & 63;
    const int wave = threadIdx.x >> 6;
    const int l15  = lane & 15;
    const int quad = lane >> 4;
    const int k0   = quad * 8;
    const int n0   = blockIdx.x * 64 + wave * 16;
    const int mbeg = blockIdx.y * (MITERS * 16);

    short8 bfrag = *reinterpret_cast<const short8*>(B + (size_t)(n0 + l15) * 32 + k0);

    const short* aptr = A + (size_t)(mbeg + l15) * 32 + k0;
    short* dptr = D + (size_t)(mbeg + l15) * N + n0 + quad * 4;
    const size_t dstep = (size_t)16 * N;

    short8 a_cur = *reinterpret_cast<const short8*>(aptr);
    #pragma unroll
    for (int it = 0; it < MITERS; ++it) {
        aptr += 16 * 32;
        short8 a_nxt;
        if (it + 1 < MITERS) a_nxt = *reinterpret_cast<const short8*>(aptr);

        f32x4 acc = {0.0f, 0.0f, 0.0f, 0.0f};
        acc = __builtin_amdgcn_mfma_f32_16x16x32_bf16(bfrag, a_cur, acc, 0, 0, 0);

        bf16x4 pv = { f2bf(acc.x), f2bf(acc.y), f2bf(acc.z), f2bf(acc.w) };
        *reinterpret_cast<bf16x4*>(dptr) = pv;
        dptr += dstep;
        a_cur = a_nxt;
    }
}

// ---------------------------------------------------------------------------
// K3: K=32 skinny GEMM, fp32 out + bias. Each wave: 16 rows x 32 cols per
// iter (2 MFMAs sharing one A-frag) -> every row gets a full 128 B line per
// wave-iter. Plain (cached) dwordx4 stores; L2/MALL absorbs the 75.5 MB.
// ---------------------------------------------------------------------------
template <int MITERS>
__global__ __launch_bounds__(256, 4) void gemm_k32_f32_kernel(
    const short* __restrict__ A, const short* __restrict__ B,
    float* __restrict__ D, const float* __restrict__ bias, int N) {
    const int lane = threadIdx.x & 63;
    const int wave = threadIdx.x >> 6;
    const int l15  = lane & 15;
    const int quad = lane >> 4;
    const int k0   = quad * 8;
    const int n0   = blockIdx.x * 128 + wave * 32;  // 32-wide n window per wave
    const int mbeg = blockIdx.y * (MITERS * 16);

    short8 bfrag0 = *reinterpret_cast<const short8*>(B + (size_t)(n0      + l15) * 32 + k0);
    short8 bfrag1 = *reinterpret_cast<const short8*>(B + (size_t)(n0 + 16 + l15) * 32 + k0);

    f32x4 bv0 = *reinterpret_cast<const f32x4*>(bias + ((n0      + quad * 4) & 127));
    f32x4 bv1 = *reinterpret_cast<const f32x4*>(bias + ((n0 + 16 + quad * 4) & 127));

    const short* aptr = A + (size_t)(mbeg + l15) * 32 + k0;
    float* dptr = D + (size_t)(mbeg + l15) * N + n0 + quad * 4;
    const size_t dstep = (size_t)16 * N;

    short8 a_cur = *reinterpret_cast<const short8*>(aptr);
    #pragma unroll
    for (int it = 0; it < MITERS; ++it) {
        aptr += 16 * 32;
        short8 a_nxt;
        if (it + 1 < MITERS) a_nxt = *reinterpret_cast<const short8*>(aptr);

        f32x4 acc0 = {0.0f, 0.0f, 0.0f, 0.0f};
        f32x4 acc1 = {0.0f, 0.0f, 0.0f, 0.0f};
        acc0 = __builtin_amdgcn_mfma_f32_16x16x32_bf16(bfrag0, a_cur, acc0, 0, 0, 0);
        acc1 = __builtin_amdgcn_mfma_f32_16x16x32_bf16(bfrag1, a_cur, acc1, 0, 0, 0);

        *reinterpret_cast<f32x4*>(dptr)      = acc0 + bv0;
        *reinterpret_cast<f32x4*>(dptr + 16) = acc1 + bv1;
        dptr += dstep;
        a_cur = a_nxt;
    }
}

// ---------------------------------------------------------------------------
extern "C" void kernel_launch(void* const* d_in, const int* in_sizes, int n_in,
                              void* d_out, int out_size, void* d_ws, size_t ws_size,
                              hipStream_t stream) {
    const float* seq   = (const float*)d_in[0];
    const float* gamma = (const float*)d_in[1];
    const float* beta  = (const float*)d_in[2];
    const float* w1    = (const float*)d_in[3];
    const float* b1    = (const float*)d_in[4];
    const float* w2    = (const float*)d_in[5];
    const float* b2    = (const float*)d_in[6];
    const float* w3    = (const float*)d_in[7];
    const float* b3    = (const float*)d_in[8];
    float* out = (float*)d_out;

    const int L = 384, H = 32, P = 128;
    const int N2 = P * H;        // 4096
    const int N3 = L * P;        // 49152

    char* ws = (char*)d_ws;
    short* s1  = (short*)(ws);                        // 384*32*2   = 24576
    short* s2  = (short*)(ws + 24576);                // 24576
    short* w3c = (short*)(ws + 49152);                // 131072*2   = 262144
    short* T   = (short*)(ws + 311296);               // 384*4096*2 = 3145728

    // K1: LN + projections (blocks 0..383) + w3 cast (blocks 384..895)
    ln_proj_cast_kernel<<<L + (P * H * H) / 256, 256, 0, stream>>>(
        seq, gamma, beta, w1, b1, w2, b2, w3, s1, s2, w3c, L);

    // K2: T[j, p*32+d] = sum_f s2[j,f] * w3c[(p*32+d), f]   (bf16 out)
    gemm_k32_bf16_kernel<3><<<dim3(N2 / 64, 8), 256, 0, stream>>>(s2, w3c, T, N2);

    // K3: pair[i, j*128+p] = sum_d s1[i,d] * T[(j*128+p), d] + b3[p]  (fp32 out)
    // grid: 384 n-blocks (128 cols each) x 4 m-chunks (96 rows -> 6 m-tiles)
    gemm_k32_f32_kernel<6><<<dim3(N3 / 128, 4), 256, 0, stream>>>(s1, T, out, b3, N3);
}